// Round 1
// baseline (1033.067 us; speedup 1.0000x reference)
//
#include <hip/hip_runtime.h>
#include <hip/hip_bf16.h>
#include <math.h>

// Problem constants
#define L_TOK 43904          // 14*56*56 tokens
#define C_DIM 192
#define NWIN 128             // 2*8*8 windows
#define NTOK 343             // 7*7*7 tokens per window
#define NHEAD 6
#define HDIM 32
#define SCALE 0.17677669529663687f   // 32^-0.5

// map spatial token index l -> window-order row (roll -3 fused)
__device__ __forceinline__ int winrow(int l) {
    int s = l / 3136;
    int rem = l - s * 3136;
    int h = rem / 56;
    int w = rem - h * 56;
    int ps = s + 11; if (ps >= 14) ps -= 14;
    int ph = h + 53; if (ph >= 56) ph -= 56;
    int pw = w + 53; if (pw >= 56) pw -= 56;
    int wi = ((ps / 7) * 8 + ph / 7) * 8 + pw / 7;
    int tk = ((ps % 7) * 7 + ph % 7) * 7 + pw % 7;
    return wi * NTOK + tk;
}

// ---------------- K0: precompute transposed rel-pos bias biasT[h][m][n] ----------------
__global__ void bias_precompute(const float* __restrict__ table, float* __restrict__ biasT) {
    int m = blockIdx.x;                     // key token
    int ms = m / 49, mh = (m / 7) % 7, mw = m % 7;
    for (int n = threadIdx.x; n < NTOK; n += 256) {   // query token
        int ns = n / 49, nh = (n / 7) % 7, nw = n % 7;
        int idx = ((ns - ms + 6) * 13 + (nh - mh + 6)) * 13 + (nw - mw + 6);
        #pragma unroll
        for (int h = 0; h < NHEAD; ++h)
            biasT[(size_t)h * NTOK * NTOK + m * NTOK + n] = table[idx * 6 + h];
    }
}

// ---------------- K1: transpose to (L,C) + LN1 + shifted window partition ----------------
__global__ __launch_bounds__(256) void ln1_part(const float* __restrict__ x,
                                                const float* __restrict__ g, const float* __restrict__ b,
                                                float* __restrict__ xt, float* __restrict__ xw) {
    __shared__ float tile[192 * 65];
    __shared__ float red[4][64];
    __shared__ float red2[4][64];
    __shared__ float mu_s[64], rs_s[64];
    int l0 = blockIdx.x * 64;
    int tid = threadIdx.x;
    int j = tid & 63, c4 = tid >> 6;
    for (int cb = 0; cb < 192; cb += 4)
        tile[(cb + c4) * 65 + j] = x[(size_t)(cb + c4) * L_TOK + l0 + j];
    __syncthreads();
    float s = 0.f, ss = 0.f;
    for (int c = c4 * 48; c < c4 * 48 + 48; ++c) {
        float v = tile[c * 65 + j];
        s += v; ss += v * v;
    }
    red[c4][j] = s; red2[c4][j] = ss;
    __syncthreads();
    if (tid < 64) {
        float S = red[0][j] + red[1][j] + red[2][j] + red[3][j];
        float SS = red2[0][j] + red2[1][j] + red2[2][j] + red2[3][j];
        float mu = S * (1.f / 192.f);
        float var = SS * (1.f / 192.f) - mu * mu;
        mu_s[j] = mu;
        rs_s[j] = rsqrtf(var + 1e-5f);
    }
    __syncthreads();
    int wave = tid >> 6, lid = tid & 63;
    for (int t = wave; t < 64; t += 4) {
        int l = l0 + t;
        int r = winrow(l);
        float mu = mu_s[t], rs = rs_s[t];
        #pragma unroll
        for (int q = 0; q < 3; ++q) {
            int c = q * 64 + lid;
            float v = tile[c * 65 + t];
            xt[(size_t)l * 192 + c] = v;
            xw[(size_t)r * 192 + c] = (v - mu) * rs * g[c] + b[c];
        }
    }
}

// ---------------- generic f32 GEMM: C[M,N] = A[M,K]@B[K,N] + bias (opt GELU) ----------------
template<int EPI>  // 0: bias only, 1: bias + exact GELU
__global__ __launch_bounds__(256) void gemm_f32(const float* __restrict__ A, const float* __restrict__ B,
                                                const float* __restrict__ bias, float* __restrict__ C,
                                                int N, int K) {
    __shared__ float As[16][68];
    __shared__ float Bs[16][68];
    int m0 = blockIdx.x * 64;
    int n0 = blockIdx.y * 64;
    int tid = threadIdx.x;
    int tm = tid >> 4, tn = tid & 15;
    int arow = tid >> 2, aquad = tid & 3;
    int brow = tid >> 4, bcol = tid & 15;
    float acc[4][4] = {};
    for (int k0 = 0; k0 < K; k0 += 16) {
        __syncthreads();
        float4 av = *(const float4*)&A[(size_t)(m0 + arow) * K + k0 + aquad * 4];
        As[aquad * 4 + 0][arow] = av.x;
        As[aquad * 4 + 1][arow] = av.y;
        As[aquad * 4 + 2][arow] = av.z;
        As[aquad * 4 + 3][arow] = av.w;
        float4 bv = *(const float4*)&B[(size_t)(k0 + brow) * N + n0 + bcol * 4];
        *(float4*)&Bs[brow][bcol * 4] = bv;
        __syncthreads();
        #pragma unroll
        for (int kk = 0; kk < 16; ++kk) {
            float a[4], b[4];
            *(float4*)a = *(const float4*)&As[kk][tm * 4];
            *(float4*)b = *(const float4*)&Bs[kk][tn * 4];
            #pragma unroll
            for (int i = 0; i < 4; ++i)
                #pragma unroll
                for (int jj = 0; jj < 4; ++jj)
                    acc[i][jj] += a[i] * b[jj];
        }
    }
    #pragma unroll
    for (int i = 0; i < 4; ++i) {
        int row = m0 + tm * 4 + i;
        #pragma unroll
        for (int jj = 0; jj < 4; ++jj) {
            float v = acc[i][jj] + bias[n0 + tn * 4 + jj];
            if (EPI == 1) v = 0.5f * v * (1.f + erff(v * 0.70710678118654752f));
            acc[i][jj] = v;
        }
        *(float4*)&C[(size_t)row * N + n0 + tn * 4] = *(float4*)&acc[i][0];
    }
}

// ---------------- K3: windowed attention, one (window, head) per block ----------------
__global__ __launch_bounds__(512) void attn_kernel(const float* __restrict__ qkv,
                                                   const float* __restrict__ biasT,
                                                   float* __restrict__ aout) {
    int w = blockIdx.x;   // 0..127
    int h = blockIdx.y;   // 0..5
    __shared__ float ks[NTOK][32];
    __shared__ float vs[NTOK][32];
    __shared__ int reg_s[NTOK];
    int tid = threadIdx.x;
    const float* base = qkv + (size_t)w * NTOK * 576;
    for (int idx = tid; idx < NTOK * 8; idx += 512) {
        int n = idx >> 3, q4 = idx & 7;
        float4 kv = *(const float4*)&base[(size_t)n * 576 + 192 + h * 32 + q4 * 4];
        *(float4*)&ks[n][q4 * 4] = kv;
        float4 vv = *(const float4*)&base[(size_t)n * 576 + 384 + h * 32 + q4 * 4];
        *(float4*)&vs[n][q4 * 4] = vv;
    }
    int wis = w >> 6, wih = (w >> 3) & 7, wiw = w & 7;
    for (int n = tid; n < NTOK; n += 512) {
        int ts = n / 49, th = (n / 7) % 7, tw = n % 7;
        int ps = wis * 7 + ts, ph = wih * 7 + th, pw = wiw * 7 + tw;
        int rs = ps < 7 ? 0 : (ps < 11 ? 1 : 2);
        int rh = ph < 49 ? 0 : (ph < 53 ? 1 : 2);
        int rw = pw < 49 ? 0 : (pw < 53 ? 1 : 2);
        reg_s[n] = rs * 9 + rh * 3 + rw;
    }
    __syncthreads();
    if (tid >= NTOK) return;
    int n = tid;
    const float* bT = biasT + (size_t)h * NTOK * NTOK;
    float q[32];
    #pragma unroll
    for (int d4 = 0; d4 < 8; ++d4) {
        float4 qv = *(const float4*)&base[(size_t)n * 576 + h * 32 + d4 * 4];
        q[d4 * 4 + 0] = qv.x * SCALE; q[d4 * 4 + 1] = qv.y * SCALE;
        q[d4 * 4 + 2] = qv.z * SCALE; q[d4 * 4 + 3] = qv.w * SCALE;
    }
    int rn = reg_s[n];
    float mrun = -1e30f, lrun = 0.f;
    float acc[32] = {};
    for (int jt = 0; jt < NTOK; ++jt) {
        float s0 = 0.f, s1 = 0.f, s2 = 0.f, s3 = 0.f;
        #pragma unroll
        for (int d4 = 0; d4 < 8; ++d4) {
            float4 kv = *(const float4*)&ks[jt][d4 * 4];
            s0 += q[d4 * 4 + 0] * kv.x; s1 += q[d4 * 4 + 1] * kv.y;
            s2 += q[d4 * 4 + 2] * kv.z; s3 += q[d4 * 4 + 3] * kv.w;
        }
        float sc = (s0 + s1) + (s2 + s3) + bT[jt * NTOK + n];
        if (reg_s[jt] != rn) sc -= 100.f;
        if (sc > mrun) {
            float corr = __expf(mrun - sc);
            lrun *= corr;
            #pragma unroll
            for (int d = 0; d < 32; ++d) acc[d] *= corr;
            mrun = sc;
        }
        float p = __expf(sc - mrun);
        lrun += p;
        #pragma unroll
        for (int d4 = 0; d4 < 8; ++d4) {
            float4 vv = *(const float4*)&vs[jt][d4 * 4];
            acc[d4 * 4 + 0] += p * vv.x; acc[d4 * 4 + 1] += p * vv.y;
            acc[d4 * 4 + 2] += p * vv.z; acc[d4 * 4 + 3] += p * vv.w;
        }
    }
    float inv = 1.f / lrun;
    float* outp = aout + ((size_t)w * NTOK + n) * 192 + h * 32;
    #pragma unroll
    for (int d4 = 0; d4 < 8; ++d4) {
        float4 ov;
        ov.x = acc[d4 * 4 + 0] * inv; ov.y = acc[d4 * 4 + 1] * inv;
        ov.z = acc[d4 * 4 + 2] * inv; ov.w = acc[d4 * 4 + 3] * inv;
        *(float4*)&outp[d4 * 4] = ov;
    }
}

// ---------------- K5: residual scatter-add (window reverse + roll) fused with LN2 ----------------
__global__ __launch_bounds__(256) void add_res_ln2(float* __restrict__ xt, const float* __restrict__ pout,
                                                   const float* __restrict__ g, const float* __restrict__ b,
                                                   float* __restrict__ h1) {
    int l0 = blockIdx.x * 64;
    int wave = threadIdx.x >> 6, lid = threadIdx.x & 63;
    for (int t = wave; t < 64; t += 4) {
        int l = l0 + t;
        int r = winrow(l);
        float v[3];
        float s = 0.f, ss = 0.f;
        #pragma unroll
        for (int q = 0; q < 3; ++q) {
            int c = q * 64 + lid;
            float val = xt[(size_t)l * 192 + c] + pout[(size_t)r * 192 + c];
            xt[(size_t)l * 192 + c] = val;
            v[q] = val;
            s += val; ss += val * val;
        }
        #pragma unroll
        for (int off = 32; off; off >>= 1) {
            s += __shfl_xor(s, off);
            ss += __shfl_xor(ss, off);
        }
        float mu = s * (1.f / 192.f);
        float rs = rsqrtf(ss * (1.f / 192.f) - mu * mu + 1e-5f);
        #pragma unroll
        for (int q = 0; q < 3; ++q) {
            int c = q * 64 + lid;
            h1[(size_t)l * 192 + c] = (v[q] - mu) * rs * g[c] + b[c];
        }
    }
}

// ---------------- K7: final residual + transpose to (C, L) ----------------
__global__ __launch_bounds__(256) void final_out_k(const float* __restrict__ xt, const float* __restrict__ h3,
                                                   float* __restrict__ out) {
    __shared__ float tile[192 * 65];
    int l0 = blockIdx.x * 64;
    int wave = threadIdx.x >> 6, lid = threadIdx.x & 63;
    for (int t = wave; t < 64; t += 4) {
        int l = l0 + t;
        #pragma unroll
        for (int q = 0; q < 3; ++q) {
            int c = q * 64 + lid;
            tile[c * 65 + t] = xt[(size_t)l * 192 + c] + h3[(size_t)l * 192 + c];
        }
    }
    __syncthreads();
    int j = threadIdx.x & 63, c4 = threadIdx.x >> 6;
    for (int cb = 0; cb < 192; cb += 4)
        out[(size_t)(cb + c4) * L_TOK + l0 + j] = tile[(cb + c4) * 65 + j];
}

extern "C" void kernel_launch(void* const* d_in, const int* in_sizes, int n_in,
                              void* d_out, int out_size, void* d_ws, size_t ws_size,
                              hipStream_t stream) {
    const float* x      = (const float*)d_in[0];
    const float* n1g    = (const float*)d_in[1];
    const float* n1b    = (const float*)d_in[2];
    const float* qkv_w  = (const float*)d_in[3];
    const float* qkv_b  = (const float*)d_in[4];
    const float* rpb    = (const float*)d_in[5];
    const float* proj_w = (const float*)d_in[6];
    const float* proj_b = (const float*)d_in[7];
    const float* n2g    = (const float*)d_in[8];
    const float* n2b    = (const float*)d_in[9];
    const float* fc1_w  = (const float*)d_in[10];
    const float* fc1_b  = (const float*)d_in[11];
    const float* fc2_w  = (const float*)d_in[12];
    const float* fc2_b  = (const float*)d_in[13];
    float* out = (float*)d_out;

    // workspace layout (floats):
    //   xt   [L*192]  : token-major input copy / running residual
    //   bufB [L*192]  : xw -> aout -> h1 -> h3
    //   bufC [L*768]  : qkv -> pout -> h2   (biasT tucked at bufC + L*576)
    float* xt    = (float*)d_ws;
    float* bufB  = xt + (size_t)L_TOK * 192;
    float* bufC  = bufB + (size_t)L_TOK * 192;
    float* biasT = bufC + (size_t)L_TOK * 576;

    bias_precompute<<<NTOK, 256, 0, stream>>>(rpb, biasT);
    ln1_part<<<686, 256, 0, stream>>>(x, n1g, n1b, xt, bufB);
    // QKV: (L,192)@(192,576)
    gemm_f32<0><<<dim3(686, 9), 256, 0, stream>>>(bufB, qkv_w, qkv_b, bufC, 576, 192);
    // attention: qkv(bufC) -> aout(bufB)
    attn_kernel<<<dim3(NWIN, NHEAD), 512, 0, stream>>>(bufC, biasT, bufB);
    // proj: (L,192)@(192,192) -> pout(bufC)
    gemm_f32<0><<<dim3(686, 3), 256, 0, stream>>>(bufB, proj_w, proj_b, bufC, 192, 192);
    // xt += pout[winrow(l)]; h1(bufB) = LN2(xt)
    add_res_ln2<<<686, 256, 0, stream>>>(xt, bufC, n2g, n2b, bufB);
    // fc1+GELU: (L,192)@(192,768) -> h2(bufC)
    gemm_f32<1><<<dim3(686, 12), 256, 0, stream>>>(bufB, fc1_w, fc1_b, bufC, 768, 192);
    // fc2: (L,768)@(768,192) -> h3(bufB)
    gemm_f32<0><<<dim3(686, 3), 256, 0, stream>>>(bufC, fc2_w, fc2_b, bufB, 192, 768);
    // out[c*L + l] = xt[l,c] + h3[l,c]
    final_out_k<<<686, 256, 0, stream>>>(xt, bufB, out);
}

// Round 2
// 279.128 us; speedup vs baseline: 3.7011x; 3.7011x over previous
//
#include <hip/hip_runtime.h>
#include <hip/hip_bf16.h>
#include <math.h>

#define L_TOK 43904          // 14*56*56 tokens
#define NWIN 128
#define NTOK 343
#define NHEAD 6
#define HDIM 32
#define SCALE 0.17677669529663687f

typedef __attribute__((ext_vector_type(8))) short short8;
typedef __attribute__((ext_vector_type(4))) float f32x4;

__device__ __forceinline__ unsigned short f2bf(float x) {
    union { float f; unsigned int u; } v; v.f = x;
    unsigned int r = v.u + 0x7fffu + ((v.u >> 16) & 1u);
    return (unsigned short)(r >> 16);
}

// map spatial token index l -> window-order row (roll -3 fused)
__device__ __forceinline__ int winrow(int l) {
    int s = l / 3136;
    int rem = l - s * 3136;
    int h = rem / 56;
    int w = rem - h * 56;
    int ps = s + 11; if (ps >= 14) ps -= 14;
    int ph = h + 53; if (ph >= 56) ph -= 56;
    int pw = w + 53; if (pw >= 56) pw -= 56;
    int wi = ((ps / 7) * 8 + ph / 7) * 8 + pw / 7;
    int tk = ((ps % 7) * 7 + ph % 7) * 7 + pw % 7;
    return wi * NTOK + tk;
}

// ---------------- weight conversion: f32 [K][N] -> bf16 [N][K]; q-scale folded ----------------
__global__ __launch_bounds__(256) void convert_weights(
    const float* __restrict__ qkv_w, const float* __restrict__ qkv_b,
    const float* __restrict__ proj_w, const float* __restrict__ fc1_w,
    const float* __restrict__ fc2_w,
    unsigned short* __restrict__ qkvT, unsigned short* __restrict__ projT,
    unsigned short* __restrict__ fc1T, unsigned short* __restrict__ fc2T,
    float* __restrict__ qkvb_s) {
    int stride = gridDim.x * 256;
    int t0 = blockIdx.x * 256 + threadIdx.x;
    for (int i = t0; i < 576 * 192; i += stride) {
        int n = i / 192, k = i - n * 192;
        float v = qkv_w[k * 576 + n];
        if (n < 192) v *= SCALE;
        qkvT[i] = f2bf(v);
    }
    for (int i = t0; i < 192 * 192; i += stride) {
        int n = i / 192, k = i - n * 192;
        projT[i] = f2bf(proj_w[k * 192 + n]);
    }
    for (int i = t0; i < 768 * 192; i += stride) {
        int n = i / 192, k = i - n * 192;
        fc1T[i] = f2bf(fc1_w[k * 768 + n]);
    }
    for (int i = t0; i < 192 * 768; i += stride) {
        int n = i / 768, k = i - n * 768;
        fc2T[i] = f2bf(fc2_w[k * 192 + n]);
    }
    for (int i = t0; i < 576; i += stride) {
        float v = qkv_b[i]; if (i < 192) v *= SCALE;
        qkvb_s[i] = v;
    }
}

// ---------------- rel-pos bias, query-major: biasT[h][q][k] ----------------
__global__ void bias_precompute(const float* __restrict__ table, float* __restrict__ biasT) {
    int n = blockIdx.x;                     // query token
    int ns = n / 49, nh = (n / 7) % 7, nw = n % 7;
    for (int m = threadIdx.x; m < NTOK; m += 256) {   // key token
        int ms = m / 49, mh = (m / 7) % 7, mw = m % 7;
        int idx = ((ns - ms + 6) * 13 + (nh - mh + 6)) * 13 + (nw - mw + 6);
        #pragma unroll
        for (int h = 0; h < NHEAD; ++h)
            biasT[(size_t)h * NTOK * NTOK + n * NTOK + m] = table[idx * 6 + h];
    }
}

// ---------------- K1: transpose to (L,C) + LN1 + shifted window partition (bf16 out) ----------------
__global__ __launch_bounds__(256) void ln1_part(const float* __restrict__ x,
                                                const float* __restrict__ g, const float* __restrict__ b,
                                                float* __restrict__ xt, unsigned short* __restrict__ xw) {
    __shared__ float tile[192 * 65];
    __shared__ float red[4][64];
    __shared__ float red2[4][64];
    __shared__ float mu_s[64], rs_s[64];
    int l0 = blockIdx.x * 64;
    int tid = threadIdx.x;
    int j = tid & 63, c4 = tid >> 6;
    for (int cb = 0; cb < 192; cb += 4)
        tile[(cb + c4) * 65 + j] = x[(size_t)(cb + c4) * L_TOK + l0 + j];
    __syncthreads();
    float s = 0.f, ss = 0.f;
    for (int c = c4 * 48; c < c4 * 48 + 48; ++c) {
        float v = tile[c * 65 + j];
        s += v; ss += v * v;
    }
    red[c4][j] = s; red2[c4][j] = ss;
    __syncthreads();
    if (tid < 64) {
        float S = red[0][j] + red[1][j] + red[2][j] + red[3][j];
        float SS = red2[0][j] + red2[1][j] + red2[2][j] + red2[3][j];
        float mu = S * (1.f / 192.f);
        float var = SS * (1.f / 192.f) - mu * mu;
        mu_s[j] = mu;
        rs_s[j] = rsqrtf(var + 1e-5f);
    }
    __syncthreads();
    int wave = tid >> 6, lid = tid & 63;
    for (int t = wave; t < 64; t += 4) {
        int l = l0 + t;
        int r = winrow(l);
        float mu = mu_s[t], rs = rs_s[t];
        #pragma unroll
        for (int q = 0; q < 3; ++q) {
            int c = q * 64 + lid;
            float v = tile[c * 65 + t];
            xt[(size_t)l * 192 + c] = v;
            xw[(size_t)r * 192 + c] = f2bf((v - mu) * rs * g[c] + b[c]);
        }
    }
}

// ---------------- bf16 MFMA GEMM: C[M,N] = A[M,K] @ Bt[N,K]^T + bias ----------------
// BM=128, BN=64, BK=32. A, Bt bf16 row-major. EPI=1: exact GELU. OUTF32: f32 else bf16.
template<int EPI, int OUTF32>
__global__ __launch_bounds__(256) void gemm_bf16(
    const unsigned short* __restrict__ A, const unsigned short* __restrict__ Bt,
    const float* __restrict__ bias, void* __restrict__ Cout, int N, int K) {
    __shared__ unsigned short As[2][128][40];
    __shared__ unsigned short Bs[2][64][40];
    const int tid = threadIdx.x;
    const int m0 = blockIdx.x * 128;
    const int n0 = blockIdx.y * 64;
    const int l = tid & 63;
    const int wid = tid >> 6;
    const int wm = wid >> 1, wn = wid & 1;
    const int lr = l & 15, lg = l >> 4;

    const int ra0 = tid >> 2, ca0 = tid & 3;          // A chunk 0: rows 0..63
    const int ra1 = (tid + 256) >> 2;                 // A chunk 1: rows 64..127
    const int rb = tid >> 2, cb = tid & 3;            // B chunk

    f32x4 acc[4][2];
    #pragma unroll
    for (int i = 0; i < 4; ++i)
        #pragma unroll
        for (int jj = 0; jj < 2; ++jj)
            acc[i][jj] = (f32x4){0.f, 0.f, 0.f, 0.f};

    const int KT = K >> 5;

    // stage k-tile 0
    {
        int k0 = 0;
        short8 a0 = *(const short8*)(A + (size_t)(m0 + ra0) * K + k0 + ca0 * 8);
        short8 a1 = *(const short8*)(A + (size_t)(m0 + ra1) * K + k0 + ca0 * 8);
        short8 b0 = *(const short8*)(Bt + (size_t)(n0 + rb) * K + k0 + cb * 8);
        *(short8*)&As[0][ra0][ca0 * 8] = a0;
        *(short8*)&As[0][ra1][ca0 * 8] = a1;
        *(short8*)&Bs[0][rb][cb * 8] = b0;
    }
    __syncthreads();

    for (int kt = 0; kt < KT; ++kt) {
        int buf = kt & 1;
        if (kt + 1 < KT) {
            int k0 = (kt + 1) * 32;
            short8 a0 = *(const short8*)(A + (size_t)(m0 + ra0) * K + k0 + ca0 * 8);
            short8 a1 = *(const short8*)(A + (size_t)(m0 + ra1) * K + k0 + ca0 * 8);
            short8 b0 = *(const short8*)(Bt + (size_t)(n0 + rb) * K + k0 + cb * 8);
            *(short8*)&As[buf ^ 1][ra0][ca0 * 8] = a0;
            *(short8*)&As[buf ^ 1][ra1][ca0 * 8] = a1;
            *(short8*)&Bs[buf ^ 1][rb][cb * 8] = b0;
        }
        short8 a[4], b[2];
        #pragma unroll
        for (int i = 0; i < 4; ++i)
            a[i] = *(const short8*)&As[buf][wm * 64 + i * 16 + lr][lg * 8];
        #pragma unroll
        for (int jj = 0; jj < 2; ++jj)
            b[jj] = *(const short8*)&Bs[buf][wn * 32 + jj * 16 + lr][lg * 8];
        #pragma unroll
        for (int i = 0; i < 4; ++i)
            #pragma unroll
            for (int jj = 0; jj < 2; ++jj)
                acc[i][jj] = __builtin_amdgcn_mfma_f32_16x16x32_bf16(a[i], b[jj], acc[i][jj], 0, 0, 0);
        __syncthreads();
    }

    float bia[2];
    bia[0] = bias[n0 + wn * 32 + lr];
    bia[1] = bias[n0 + wn * 32 + 16 + lr];
    #pragma unroll
    for (int i = 0; i < 4; ++i) {
        #pragma unroll
        for (int jj = 0; jj < 2; ++jj) {
            #pragma unroll
            for (int r = 0; r < 4; ++r) {
                float v = acc[i][jj][r] + bia[jj];
                if (EPI == 1) v = 0.5f * v * (1.f + erff(v * 0.70710678118654752f));
                int row = m0 + wm * 64 + i * 16 + lg * 4 + r;
                int col = n0 + wn * 32 + jj * 16 + lr;
                if (OUTF32) ((float*)Cout)[(size_t)row * N + col] = v;
                else ((unsigned short*)Cout)[(size_t)row * N + col] = f2bf(v);
            }
        }
    }
}

// ---------------- MFMA windowed attention: one (window, head) per 256-thread block ----------------
__global__ __launch_bounds__(256) void attn_mfma(
    const unsigned short* __restrict__ qkv, const float* __restrict__ biasT,
    unsigned short* __restrict__ aout) {
    __shared__ unsigned short Ks[352][40];   // K rows, padded stride 40 bf16
    __shared__ unsigned short Vt[32][360];   // V transposed: [dim][key], stride 360
    __shared__ unsigned short Ps[4][16][40]; // per-wave P scratch
    __shared__ int regs_s[344];
    const int w = blockIdx.x, h = blockIdx.y;
    const int tid = threadIdx.x;
    const size_t base = (size_t)w * NTOK * 576;

    // stage K (bf16, contiguous 16B chunks)
    for (int idx = tid; idx < 1372; idx += 256) {
        int j = idx >> 2, c = idx & 3;
        short8 kv = *(const short8*)(qkv + base + (size_t)j * 576 + 192 + h * 32 + c * 8);
        *(short8*)&Ks[j][c * 8] = kv;
    }
    // zero-pad K rows 343..351
    for (int idx = tid; idx < 36; idx += 256) {
        int j = 343 + (idx >> 2), c = idx & 3;
        short8 z = {};
        *(short8*)&Ks[j][c * 8] = z;
    }
    // stage V transposed (pairs of rows -> ushort2 column writes)
    for (int idx = tid; idx < 688; idx += 256) {
        int jp = idx >> 2, c = idx & 3;
        int j0 = jp * 2, j1 = j0 + 1;
        short8 v0 = *(const short8*)(qkv + base + (size_t)j0 * 576 + 384 + h * 32 + c * 8);
        short8 v1 = {};
        if (j1 < NTOK) v1 = *(const short8*)(qkv + base + (size_t)j1 * 576 + 384 + h * 32 + c * 8);
        #pragma unroll
        for (int i = 0; i < 8; ++i) {
            ushort2 pr;
            pr.x = (unsigned short)v0[i];
            pr.y = (unsigned short)v1[i];
            *(ushort2*)&Vt[c * 8 + i][j0] = pr;
        }
    }
    // zero-pad Vt cols 344..351
    for (int idx = tid; idx < 128; idx += 256) {
        int d = idx >> 2;
        ushort2 z; z.x = 0; z.y = 0;
        *(ushort2*)&Vt[d][344 + (idx & 3) * 2] = z;
    }
    // mask regions
    {
        const int wis = w >> 6, wih = (w >> 3) & 7, wiw = w & 7;
        for (int n = tid; n < NTOK; n += 256) {
            int ts = n / 49, r49 = n - ts * 49, th = r49 / 7, tw = r49 - th * 7;
            int ps = wis * 7 + ts, ph = wih * 7 + th, pw = wiw * 7 + tw;
            int rs = ps < 7 ? 0 : (ps < 11 ? 1 : 2);
            int rh = ph < 49 ? 0 : (ph < 53 ? 1 : 2);
            int rw = pw < 49 ? 0 : (pw < 53 ? 1 : 2);
            regs_s[n] = rs * 9 + rh * 3 + rw;
        }
    }
    __syncthreads();

    const int wid = tid >> 6, l = tid & 63, lr = l & 15, lg = l >> 4;
    const float* bh = biasT + (size_t)h * NTOK * NTOK;

    for (int qt = wid; qt < 22; qt += 4) {
        // Q A-fragment straight from global (q pre-scaled in weights)
        int qrow = qt * 16 + lr;
        int qr = qrow < NTOK ? qrow : 0;
        short8 qa = *(const short8*)(qkv + base + (size_t)qr * 576 + h * 32 + lg * 8);

        f32x4 s[22];
        const f32x4 zv = (f32x4){0.f, 0.f, 0.f, 0.f};
        #pragma unroll
        for (int kt = 0; kt < 22; ++kt) {
            short8 kf = *(const short8*)&Ks[kt * 16 + lr][lg * 8];
            s[kt] = __builtin_amdgcn_mfma_f32_16x16x32_bf16(qa, kf, zv, 0, 0, 0);
        }

        // bias + shift-mask + key-validity
        int qrw[4], rq[4];
        #pragma unroll
        for (int r = 0; r < 4; ++r) {
            int q = qt * 16 + lg * 4 + r;
            qrw[r] = q < NTOK ? q : NTOK - 1;
            rq[r] = regs_s[qrw[r]];
        }
        #pragma unroll
        for (int kt = 0; kt < 22; ++kt) {
            int jj = kt * 16 + lr;
            int jm = jj < NTOK ? jj : NTOK - 1;
            int kr = regs_s[jm];
            bool jv = jj < NTOK;
            #pragma unroll
            for (int r = 0; r < 4; ++r) {
                float v = s[kt][r] + bh[(size_t)qrw[r] * NTOK + jm] + (kr != rq[r] ? -100.f : 0.f);
                s[kt][r] = jv ? v : -1e30f;
            }
        }

        // row softmax (16-lane group reductions; rows match O-frag rows)
        float inv[4];
        #pragma unroll
        for (int r = 0; r < 4; ++r) {
            float m = -1e30f;
            #pragma unroll
            for (int kt = 0; kt < 22; ++kt) m = fmaxf(m, s[kt][r]);
            #pragma unroll
            for (int off = 1; off < 16; off <<= 1) m = fmaxf(m, __shfl_xor(m, off));
            float sum = 0.f;
            #pragma unroll
            for (int kt = 0; kt < 22; ++kt) {
                float p = __expf(s[kt][r] - m);
                s[kt][r] = p;
                sum += p;
            }
            #pragma unroll
            for (int off = 1; off < 16; off <<= 1) sum += __shfl_xor(sum, off);
            inv[r] = 1.f / sum;
        }

        // PV: 11 key-blocks of 32, P bounced through per-wave LDS scratch
        f32x4 o0 = (f32x4){0.f, 0.f, 0.f, 0.f};
        f32x4 o1 = (f32x4){0.f, 0.f, 0.f, 0.f};
        #pragma unroll
        for (int kb = 0; kb < 11; ++kb) {
            #pragma unroll
            for (int r = 0; r < 4; ++r) {
                Ps[wid][lg * 4 + r][lr] = f2bf(s[2 * kb][r]);
                Ps[wid][lg * 4 + r][lr + 16] = f2bf(s[2 * kb + 1][r]);
            }
            short8 pa = *(const short8*)&Ps[wid][lr][lg * 8];
            short8 v0 = *(const short8*)&Vt[lr][kb * 32 + lg * 8];
            short8 v1 = *(const short8*)&Vt[16 + lr][kb * 32 + lg * 8];
            o0 = __builtin_amdgcn_mfma_f32_16x16x32_bf16(pa, v0, o0, 0, 0, 0);
            o1 = __builtin_amdgcn_mfma_f32_16x16x32_bf16(pa, v1, o1, 0, 0, 0);
        }

        #pragma unroll
        for (int r = 0; r < 4; ++r) {
            int q = qt * 16 + lg * 4 + r;
            if (q < NTOK) {
                size_t orow = ((size_t)w * NTOK + q) * 192 + h * 32;
                aout[orow + lr] = f2bf(o0[r] * inv[r]);
                aout[orow + 16 + lr] = f2bf(o1[r] * inv[r]);
            }
        }
    }
}

// ---------------- K5: residual scatter-add (window reverse + roll) fused with LN2 ----------------
__global__ __launch_bounds__(256) void add_res_ln2(float* __restrict__ xt, const float* __restrict__ pout,
                                                   const float* __restrict__ g, const float* __restrict__ b,
                                                   unsigned short* __restrict__ h1) {
    int l0 = blockIdx.x * 64;
    int wave = threadIdx.x >> 6, lid = threadIdx.x & 63;
    for (int t = wave; t < 64; t += 4) {
        int l = l0 + t;
        int r = winrow(l);
        float v[3];
        float s = 0.f, ss = 0.f;
        #pragma unroll
        for (int q = 0; q < 3; ++q) {
            int c = q * 64 + lid;
            float val = xt[(size_t)l * 192 + c] + pout[(size_t)r * 192 + c];
            xt[(size_t)l * 192 + c] = val;
            v[q] = val;
            s += val; ss += val * val;
        }
        #pragma unroll
        for (int off = 32; off; off >>= 1) {
            s += __shfl_xor(s, off);
            ss += __shfl_xor(ss, off);
        }
        float mu = s * (1.f / 192.f);
        float rs = rsqrtf(ss * (1.f / 192.f) - mu * mu + 1e-5f);
        #pragma unroll
        for (int q = 0; q < 3; ++q) {
            int c = q * 64 + lid;
            h1[(size_t)l * 192 + c] = f2bf((v[q] - mu) * rs * g[c] + b[c]);
        }
    }
}

// ---------------- K7: final residual + transpose to (C, L) ----------------
__global__ __launch_bounds__(256) void final_out_k(const float* __restrict__ xt, const float* __restrict__ h3,
                                                   float* __restrict__ out) {
    __shared__ float tile[192 * 65];
    int l0 = blockIdx.x * 64;
    int wave = threadIdx.x >> 6, lid = threadIdx.x & 63;
    for (int t = wave; t < 64; t += 4) {
        int l = l0 + t;
        #pragma unroll
        for (int q = 0; q < 3; ++q) {
            int c = q * 64 + lid;
            tile[c * 65 + t] = xt[(size_t)l * 192 + c] + h3[(size_t)l * 192 + c];
        }
    }
    __syncthreads();
    int j = threadIdx.x & 63, c4 = threadIdx.x >> 6;
    for (int cb = 0; cb < 192; cb += 4)
        out[(size_t)(cb + c4) * L_TOK + l0 + j] = tile[(cb + c4) * 65 + j];
}

extern "C" void kernel_launch(void* const* d_in, const int* in_sizes, int n_in,
                              void* d_out, int out_size, void* d_ws, size_t ws_size,
                              hipStream_t stream) {
    const float* x      = (const float*)d_in[0];
    const float* n1g    = (const float*)d_in[1];
    const float* n1b    = (const float*)d_in[2];
    const float* qkv_w  = (const float*)d_in[3];
    const float* qkv_b  = (const float*)d_in[4];
    const float* rpb    = (const float*)d_in[5];
    const float* proj_w = (const float*)d_in[6];
    const float* proj_b = (const float*)d_in[7];
    const float* n2g    = (const float*)d_in[8];
    const float* n2b    = (const float*)d_in[9];
    const float* fc1_w  = (const float*)d_in[10];
    const float* fc1_b  = (const float*)d_in[11];
    const float* fc2_w  = (const float*)d_in[12];
    const float* fc2_b  = (const float*)d_in[13];
    float* out = (float*)d_out;

    // workspace layout
    char* p = (char*)d_ws;
    float* xt = (float*)p;                 p += (size_t)L_TOK * 192 * 4;   // residual, f32
    float* pout = (float*)p;               // proj out f32; later h3 (fc2 out f32)
    float* h3 = pout;                      p += (size_t)L_TOK * 192 * 4;
    unsigned short* xw = (unsigned short*)p;   // LN1 out bf16; later h1 (LN2 out bf16)
    unsigned short* h1 = xw;               p += (size_t)L_TOK * 192 * 2;
    unsigned short* qkvb = (unsigned short*)p; // qkv bf16 [L][576]; later h2 overlays [L][768]
    unsigned short* h2 = qkvb;             p += (size_t)L_TOK * 576 * 2;
    unsigned short* aoutb = (unsigned short*)p; p += (size_t)L_TOK * 192 * 2; // attn out bf16
    float* biasT = (float*)p;              p += (size_t)NHEAD * NTOK * NTOK * 4;
    unsigned short* qkvT = (unsigned short*)p; p += (size_t)576 * 192 * 2;
    unsigned short* projT = (unsigned short*)p; p += (size_t)192 * 192 * 2;
    unsigned short* fc1T = (unsigned short*)p; p += (size_t)768 * 192 * 2;
    unsigned short* fc2T = (unsigned short*)p; p += (size_t)192 * 768 * 2;
    float* qkvb_s = (float*)p;             p += 576 * 4;

    convert_weights<<<576, 256, 0, stream>>>(qkv_w, qkv_b, proj_w, fc1_w, fc2_w,
                                             qkvT, projT, fc1T, fc2T, qkvb_s);
    bias_precompute<<<NTOK, 256, 0, stream>>>(rpb, biasT);
    ln1_part<<<686, 256, 0, stream>>>(x, n1g, n1b, xt, xw);
    // QKV: (L,192)@(192,576) -> bf16, q pre-scaled
    gemm_bf16<0, 0><<<dim3(343, 9), 256, 0, stream>>>(xw, qkvT, qkvb_s, qkvb, 576, 192);
    // attention -> aoutb bf16
    attn_mfma<<<dim3(NWIN, NHEAD), 256, 0, stream>>>(qkvb, biasT, aoutb);
    // proj: (L,192)@(192,192) -> f32
    gemm_bf16<0, 1><<<dim3(343, 3), 256, 0, stream>>>(aoutb, projT, proj_b, pout, 192, 192);
    // xt += pout[winrow(l)]; h1 = LN2(xt) bf16
    add_res_ln2<<<686, 256, 0, stream>>>(xt, pout, n2g, n2b, h1);
    // fc1+GELU: (L,192)@(192,768) -> bf16 (overlays dead qkv/aout region)
    gemm_bf16<1, 0><<<dim3(343, 12), 256, 0, stream>>>(h1, fc1T, fc1_b, h2, 768, 192);
    // fc2: (L,768)@(768,192) -> f32 (overlays dead pout)
    gemm_bf16<0, 1><<<dim3(343, 3), 256, 0, stream>>>(h2, fc2T, fc2_b, h3, 192, 768);
    // out[c*L + l] = xt[l,c] + h3[l,c]
    final_out_k<<<686, 256, 0, stream>>>(xt, h3, out);
}